// Round 4
// baseline (147.711 us; speedup 1.0000x reference)
//
#include <hip/hip_runtime.h>

#define EPS 1.1920928955078125e-07f

// Problem constants (hard-coded so loops fully unroll)
#define BB 32
#define TT 256000
#define T4 (TT / 4)               // 64000 float4 per stream per batch
#define WPB 50                    // waves per batch element
#define ITW 20                    // iterations per wave (WPB*ITW*64 == T4)
#define WCHUNK (ITW * 64)         // 1280 float4 per wave per stream
#define NWAVE (BB * WPB)          // 1600 independent waves
#define NBLK (NWAVE / 4)          // 400 blocks of 4 waves

// ws layout: NWAVE x 12 wave partials (float) = 76.8 KB scratch.
// Nothing in ws is read before being written in the same dispatch sequence,
// so workspace poisoning between calls is harmless.
//
// 12 per-batch statistics (raw sums; zero-meaning folded in at finalize):
// [0] sum p0   [1] sum p1   [2] sum t0   [3] sum t1
// [4] sum p0^2 [5] sum p1^2 [6] sum t0^2 [7] sum t1^2
// [8] sum p0*t0 [9] sum p0*t1 [10] sum p1*t0 [11] sum p1*t1

// Async global->LDS DMA: 64 lanes x 16 B = 1024 B per call, no VGPR round-trip.
// LDS dest must be wave-uniform (lane*16 is implicit); global src is per-lane.
__device__ __forceinline__ void gload16(const float4* g, float4* l)
{
    __builtin_amdgcn_global_load_lds(
        (const __attribute__((address_space(1))) void*)(const void*)g,
        (__attribute__((address_space(3))) void*)(void*)l,
        16, 0, 0);
}

// Barrier-free, per-wave software-pipelined streaming reduction.
// Each wave owns a 1280-float4 slice of one batch element and stages all
// 4 streams for itself: no cross-wave LDS sharing -> no __syncthreads at all.
// Double-buffered DMA with counted vmcnt(4) (T4: never drain to 0 mid-loop).
__global__ __launch_bounds__(256, 8) void pit_partials(
    const float* __restrict__ preds, const float* __restrict__ targets,
    float* __restrict__ ws)
{
    // per wave: 2 bufs x 4 streams x 64 float4 = 512 float4 (8 KB); block 32 KB
    __shared__ float4 lds4[4 * 512];

    const int tid  = threadIdx.x;
    const int lane = tid & 63;
    const int wave = tid >> 6;
    const int w = blockIdx.x * 4 + wave;     // global wave id, 0..1599
    const int b = w / WPB;                   // batch element
    const int s = w % WPB;                   // slice within batch element

    const float4* p0 = (const float4*)(preds   + (size_t)(b * 2 + 0) * TT);
    const float4* p1 = (const float4*)(preds   + (size_t)(b * 2 + 1) * TT);
    const float4* t0 = (const float4*)(targets + (size_t)(b * 2 + 0) * TT);
    const float4* t1 = (const float4*)(targets + (size_t)(b * 2 + 1) * TT);

    const int base = s * WCHUNK + lane;      // per-lane float4 index
    float4* ldsw = &lds4[wave * 512];        // this wave's private region

// issue 4 DMA loads (4 KB) for iteration j into buffer (j&1)
#define STAGE(j) do {                                   \
        const int _off = base + (j) * 64;               \
        float4* _d = ldsw + (((j) & 1) * 256);          \
        gload16(p0 + _off, _d);                         \
        gload16(p1 + _off, _d + 64);                    \
        gload16(t0 + _off, _d + 128);                   \
        gload16(t1 + _off, _d + 192);                   \
    } while (0)

    float acc[12];
#pragma unroll
    for (int k = 0; k < 12; ++k) acc[k] = 0.f;

    STAGE(0);                                // prologue: 4 loads in flight

#pragma unroll
    for (int it = 0; it < ITW; ++it) {
        if (it + 1 < ITW) {
            STAGE(it + 1);                   // 8 outstanding now
            // release current buffer's 4 loads; keep next buffer's 4 in flight
            asm volatile("s_waitcnt vmcnt(4)" ::: "memory");
        } else {
            asm volatile("s_waitcnt vmcnt(0)" ::: "memory");
        }
        __builtin_amdgcn_sched_barrier(0);   // pin: no ds_read hoisted above wait

        const int i = ((it & 1) * 256) + lane;
        float4 a0 = ldsw[i      ];           // lane-contiguous ds_read_b128:
        float4 a1 = ldsw[i +  64];           // 2 lanes/bank aliasing = free
        float4 b0 = ldsw[i + 128];
        float4 b1 = ldsw[i + 192];
#pragma unroll
        for (int e = 0; e < 4; ++e) {
            float u0 = (&a0.x)[e], u1 = (&a1.x)[e];
            float v0 = (&b0.x)[e], v1 = (&b1.x)[e];
            acc[0]  += u0;       acc[1]  += u1;
            acc[2]  += v0;       acc[3]  += v1;
            acc[4]  += u0 * u0;  acc[5]  += u1 * u1;
            acc[6]  += v0 * v0;  acc[7]  += v1 * v1;
            acc[8]  += u0 * v0;  acc[9]  += u0 * v1;
            acc[10] += u1 * v0;  acc[11] += u1 * v1;
        }
    }
#undef STAGE

    // wave(64)-level shuffle reduction; once per 80 KB of input (was per 8 KB)
#pragma unroll
    for (int k = 0; k < 12; ++k) {
        float v = acc[k];
        for (int off = 32; off > 0; off >>= 1) v += __shfl_down(v, off);
        acc[k] = v;   // valid in lane 0
    }

    if (lane == 0) {
        float* o = ws + (size_t)w * 12;
#pragma unroll
        for (int k = 0; k < 12; ++k) o[k] = acc[k];
    }
}

// Reduce NWAVE x 12 partials -> B x 12 stats -> SI-SNR -> PIT -> scalar loss
__global__ __launch_bounds__(256) void pit_final(
    const float* __restrict__ ws, float* __restrict__ out)
{
    __shared__ float sums[BB * 12];   // 384 stat slots
    __shared__ float bests[BB];

    // each thread owns 1-2 (b,k) stat slots; sums 50 wave-partials each
    for (int s = threadIdx.x; s < BB * 12; s += 256) {
        const int b = s / 12;
        const int k = s % 12;
        float v = 0.f;
        const float* base = ws + (size_t)(b * WPB) * 12 + k;
#pragma unroll 10
        for (int c = 0; c < WPB; ++c) v += base[(size_t)c * 12];
        sums[s] = v;
    }
    __syncthreads();

    if (threadIdx.x < BB) {
        const float* w = sums + threadIdx.x * 12;
        const float invT = 1.0f / (float)TT;
        float pp0 = w[4] - w[0] * w[0] * invT;
        float pp1 = w[5] - w[1] * w[1] * invT;
        float tt0 = w[6] - w[2] * w[2] * invT;
        float tt1 = w[7] - w[3] * w[3] * invT;
        float d00 = w[8]  - w[0] * w[2] * invT;
        float d01 = w[9]  - w[0] * w[3] * invT;
        float d10 = w[10] - w[1] * w[2] * invT;
        float d11 = w[11] - w[1] * w[3] * invT;

        auto sisnr = [](float dot, float pp, float tt) -> float {
            float alpha = dot / (tt + EPS);
            float st    = alpha * alpha * tt;
            float noise = pp - 2.0f * alpha * dot + st;
            return 10.0f * log10f((st + EPS) / (noise + EPS));
        };
        float s00 = sisnr(d00, pp0, tt0);
        float s01 = sisnr(d01, pp0, tt1);
        float s10 = sisnr(d10, pp1, tt0);
        float s11 = sisnr(d11, pp1, tt1);

        float perm0 = 0.5f * (s00 + s11);   // identity permutation
        float perm1 = 0.5f * (s01 + s10);   // swapped permutation
        bests[threadIdx.x] = fmaxf(perm0, perm1);
    }
    __syncthreads();

    if (threadIdx.x == 0) {
        float acc = 0.f;
#pragma unroll
        for (int b = 0; b < BB; ++b) acc += bests[b];
        out[0] = -acc / (float)BB;
    }
}

extern "C" void kernel_launch(void* const* d_in, const int* in_sizes, int n_in,
                              void* d_out, int out_size, void* d_ws, size_t ws_size,
                              hipStream_t stream)
{
    const float* preds   = (const float*)d_in[0];
    const float* targets = (const float*)d_in[1];
    float* out = (float*)d_out;
    float* ws  = (float*)d_ws;   // NWAVE*12 floats = 76,800 B of scratch

    pit_partials<<<dim3(NBLK), dim3(256), 0, stream>>>(preds, targets, ws);
    pit_final<<<dim3(1), dim3(256), 0, stream>>>(ws, out);
}

// Round 7
// 142.078 us; speedup vs baseline: 1.0396x; 1.0396x over previous
//
#include <hip/hip_runtime.h>

#define EPS 1.1920928955078125e-07f

// Problem constants (hard-coded so loops fully unroll)
#define BB 32
#define TT 256000
#define CHUNKS 50                 // chunks per batch element
#define T4 (TT / 4)               // 64000 float4 per signal
#define CHUNK (T4 / CHUNKS)       // 1280 float4 per block
#define ITERS (CHUNK / 256)       // 5 iterations per thread
#define NBLK (BB * CHUNKS)        // 1600 partial blocks

// native 16-byte vector so __builtin_nontemporal_load applies
typedef float v4f __attribute__((ext_vector_type(4)));

// ws layout: NBLK x 12 chunk partials (float) = 76.8 KB scratch.
// Nothing in ws is read before being written in the same dispatch sequence,
// so workspace poisoning between calls is harmless.
//
// 12 per-batch statistics (raw sums; zero-meaning folded in at finalize):
// [0] sum p0   [1] sum p1   [2] sum t0   [3] sum t1
// [4] sum p0^2 [5] sum p1^2 [6] sum t0^2 [7] sum t1^2
// [8] sum p0*t0 [9] sum p0*t1 [10] sum p1*t0 [11] sum p1*t1

// A/B experiment vs the round-0 baseline: IDENTICAL structure, but every
// stream load is non-temporal (L1-bypass). Read-once streaming data pays an
// L1 read-allocate fill per line that serves zero future hits; if the
// ~4.7 B/cy/CU read cap observed across R0/R3/R4 lives in L1 fill
// serialization, nt-loads remove it. Compiler-modeled (no inline-asm
// register/vmcnt hazards -- the R5/R6 failure modes).
__global__ __launch_bounds__(256, 4) void pit_partials(
    const float* __restrict__ preds, const float* __restrict__ targets,
    float* __restrict__ ws)
{
    const int b = blockIdx.x / CHUNKS;
    const int c = blockIdx.x % CHUNKS;

    const v4f* p0 = (const v4f*)(preds   + (size_t)(b * 2 + 0) * TT);
    const v4f* p1 = (const v4f*)(preds   + (size_t)(b * 2 + 1) * TT);
    const v4f* t0 = (const v4f*)(targets + (size_t)(b * 2 + 0) * TT);
    const v4f* t1 = (const v4f*)(targets + (size_t)(b * 2 + 1) * TT);

    float acc[12];
#pragma unroll
    for (int k = 0; k < 12; ++k) acc[k] = 0.f;

    const int base = c * CHUNK + (int)threadIdx.x;
#pragma unroll
    for (int it = 0; it < ITERS; ++it) {
        const int i = base + it * 256;
        v4f a0 = __builtin_nontemporal_load(p0 + i);
        v4f a1 = __builtin_nontemporal_load(p1 + i);
        v4f b0 = __builtin_nontemporal_load(t0 + i);
        v4f b1 = __builtin_nontemporal_load(t1 + i);
#pragma unroll
        for (int e = 0; e < 4; ++e) {
            float u0 = a0[e], u1 = a1[e];
            float v0 = b0[e], v1 = b1[e];
            acc[0]  += u0;       acc[1]  += u1;
            acc[2]  += v0;       acc[3]  += v1;
            acc[4]  += u0 * u0;  acc[5]  += u1 * u1;
            acc[6]  += v0 * v0;  acc[7]  += v1 * v1;
            acc[8]  += u0 * v0;  acc[9]  += u0 * v1;
            acc[10] += u1 * v0;  acc[11] += u1 * v1;
        }
    }

    // wave(64)-level shuffle reduction for all 12 stats
    const int lane = threadIdx.x & 63;
    const int wave = threadIdx.x >> 6;
#pragma unroll
    for (int k = 0; k < 12; ++k) {
        float v = acc[k];
        for (int off = 32; off > 0; off >>= 1) v += __shfl_down(v, off);
        acc[k] = v;   // valid in lane 0 of each wave
    }

    __shared__ float lds[4][12];
    if (lane == 0) {
#pragma unroll
        for (int k = 0; k < 12; ++k) lds[wave][k] = acc[k];
    }
    __syncthreads();

    // threads 0..11: sum the 4 wave-partials, plain store (no atomics)
    if (threadIdx.x < 12) {
        float v = lds[0][threadIdx.x] + lds[1][threadIdx.x]
                + lds[2][threadIdx.x] + lds[3][threadIdx.x];
        ws[(size_t)blockIdx.x * 12 + threadIdx.x] = v;
    }
}

// Reduce NBLK x 12 partials -> B x 12 stats -> SI-SNR -> PIT -> scalar loss
__global__ __launch_bounds__(256) void pit_final(
    const float* __restrict__ ws, float* __restrict__ out)
{
    __shared__ float sums[BB * 12];   // 384 stat slots
    __shared__ float bests[BB];

    // each thread owns 1-2 (b,k) stat slots; sums 50 chunk-partials each
    for (int s = threadIdx.x; s < BB * 12; s += 256) {
        const int b = s / 12;
        const int k = s % 12;
        float v = 0.f;
        const float* base = ws + (size_t)(b * CHUNKS) * 12 + k;
#pragma unroll 10
        for (int c = 0; c < CHUNKS; ++c) v += base[(size_t)c * 12];
        sums[s] = v;
    }
    __syncthreads();

    if (threadIdx.x < BB) {
        const float* w = sums + threadIdx.x * 12;
        const float invT = 1.0f / (float)TT;
        float pp0 = w[4] - w[0] * w[0] * invT;
        float pp1 = w[5] - w[1] * w[1] * invT;
        float tt0 = w[6] - w[2] * w[2] * invT;
        float tt1 = w[7] - w[3] * w[3] * invT;
        float d00 = w[8]  - w[0] * w[2] * invT;
        float d01 = w[9]  - w[0] * w[3] * invT;
        float d10 = w[10] - w[1] * w[2] * invT;
        float d11 = w[11] - w[1] * w[3] * invT;

        auto sisnr = [](float dot, float pp, float tt) -> float {
            float alpha = dot / (tt + EPS);
            float st    = alpha * alpha * tt;
            float noise = pp - 2.0f * alpha * dot + st;
            return 10.0f * log10f((st + EPS) / (noise + EPS));
        };
        float s00 = sisnr(d00, pp0, tt0);
        float s01 = sisnr(d01, pp0, tt1);
        float s10 = sisnr(d10, pp1, tt0);
        float s11 = sisnr(d11, pp1, tt1);

        float perm0 = 0.5f * (s00 + s11);   // identity permutation
        float perm1 = 0.5f * (s01 + s10);   // swapped permutation
        bests[threadIdx.x] = fmaxf(perm0, perm1);
    }
    __syncthreads();

    if (threadIdx.x == 0) {
        float acc = 0.f;
#pragma unroll
        for (int b = 0; b < BB; ++b) acc += bests[b];
        out[0] = -acc / (float)BB;
    }
}

extern "C" void kernel_launch(void* const* d_in, const int* in_sizes, int n_in,
                              void* d_out, int out_size, void* d_ws, size_t ws_size,
                              hipStream_t stream)
{
    const float* preds   = (const float*)d_in[0];
    const float* targets = (const float*)d_in[1];
    float* out = (float*)d_out;
    float* ws  = (float*)d_ws;   // NBLK*12 floats = 76,800 B of scratch

    pit_partials<<<dim3(NBLK), dim3(256), 0, stream>>>(preds, targets, ws);
    pit_final<<<dim3(1), dim3(256), 0, stream>>>(ws, out);
}